// Round 13
// baseline (224.227 us; speedup 1.0000x reference)
//
#include <hip/hip_runtime.h>
#include <math.h>

#define N_NODES    100000
#define N_EDGES    1600000
#define HIDDEN     128
#define NUM_GRAPHS 64

constexpr int POOL_CHUNKS = 16;   // kept only for workspace layout compatibility

// ---- two-level LDS-staged CSR build ----
constexpr int BINSHIFT = 10;
constexpr int BINSZ    = 1 << BINSHIFT;                  // 1024 nodes per bin
constexpr int NBIN     = (N_NODES + BINSZ - 1) / BINSZ;  // 98
constexpr int CH_E     = 8192;                           // edges per chunk
constexpr int NCH      = (N_EDGES + CH_E - 1) / CH_E;    // 196
constexpr int CAP1     = 160;  // per (bin,chunk): mean 84, +8.3 sigma
constexpr int CAP2     = 18432; // per bin: mean 16384, +16 sigma

// ---------------- bf16 helpers ----------------

static __device__ __forceinline__ unsigned short f2bf(float f) {
    unsigned u = __float_as_uint(f);
    u += 0x7FFFu + ((u >> 16) & 1u);
    return (unsigned short)(u >> 16);
}
static __device__ __forceinline__ float b2f(unsigned short h) {
    return __uint_as_float(((unsigned)h) << 16);
}

// ---------------- fp8 e4m3fn helpers (OCP, native on gfx950) ----------------

typedef float floatx2 __attribute__((ext_vector_type(2)));
typedef short bf16x8  __attribute__((ext_vector_type(8)));
typedef float f32x4v  __attribute__((ext_vector_type(4)));

#if __has_builtin(__builtin_amdgcn_cvt_pk_f32_fp8) && __has_builtin(__builtin_amdgcn_cvt_pk_fp8_f32)
#define FP8_HW 1
#else
#define FP8_HW 0
#endif

static __device__ __forceinline__ float4 dec4_e4m3(unsigned u) {
#if FP8_HW
    floatx2 lo = __builtin_amdgcn_cvt_pk_f32_fp8((int)u, false);
    floatx2 hi = __builtin_amdgcn_cvt_pk_f32_fp8((int)u, true);
    return make_float4(lo[0], lo[1], hi[0], hi[1]);
#else
    float t[4];
    #pragma unroll
    for (int i = 0; i < 4; ++i) {
        unsigned x = (u >> (8 * i)) & 0xFFu;
        unsigned s = x >> 7, e = (x >> 3) & 15u, m = x & 7u;
        float fn = __uint_as_float((s << 31) | ((e + 120u) << 23) | (m << 20));
        float fs = (float)m * 0.001953125f;
        if (s) fs = -fs;
        t[i] = e ? fn : fs;
    }
    return make_float4(t[0], t[1], t[2], t[3]);
#endif
}

static __device__ __forceinline__ unsigned char enc1_e4m3(float v) {
    unsigned u = __float_as_uint(v);
    unsigned s = u >> 31;
    float a = fabsf(v);
    if (a >= 448.f) return (unsigned char)((s << 7) | 0x7Eu);
    if (a < 0.015625f) {
        unsigned q = (unsigned)rintf(a * 512.f);
        return (unsigned char)((s << 7) | q);
    }
    unsigned au = u & 0x7FFFFFFFu;
    au += 0x7FFFFu + ((au >> 20) & 1u);
    unsigned e = (au >> 23) - 120u;
    unsigned m = (au >> 20) & 7u;
    if (e >= 15u && m >= 7u) { e = 15u; m = 6u; }
    return (unsigned char)((s << 7) | (e << 3) | m);
}

static __device__ __forceinline__ unsigned enc4_e4m3(float a, float b, float c, float d) {
#if FP8_HW
    int v = 0;
    v = __builtin_amdgcn_cvt_pk_fp8_f32(a, b, v, false);
    v = __builtin_amdgcn_cvt_pk_fp8_f32(c, d, v, true);
    return (unsigned)v;
#else
    return (unsigned)enc1_e4m3(a) | ((unsigned)enc1_e4m3(b) << 8) |
           ((unsigned)enc1_e4m3(c) << 16) | ((unsigned)enc1_e4m3(d) << 24);
#endif
}

// decode 16 fp8 (uint4) into f[16]
static __device__ __forceinline__ void dec16(uint4 v, float* f) {
    float4 a = dec4_e4m3(v.x), b = dec4_e4m3(v.y), c = dec4_e4m3(v.z), d = dec4_e4m3(v.w);
    f[0]=a.x; f[1]=a.y; f[2]=a.z; f[3]=a.w;
    f[4]=b.x; f[5]=b.y; f[6]=b.z; f[7]=b.w;
    f[8]=c.x; f[9]=c.y; f[10]=c.z; f[11]=c.w;
    f[12]=d.x; f[13]=d.y; f[14]=d.z; f[15]=d.w;
}

// ---------------- graph boundaries (batch is sorted) ----------------

__global__ void k_gbounds(const int* __restrict__ batch, int* __restrict__ gstart) {
    int i = blockIdx.x * blockDim.x + threadIdx.x;
    if (i >= N_NODES) return;
    int b = batch[i];
    if (i == 0) {
        for (int g = 0; g <= b; ++g) gstart[g] = 0;
    } else {
        int bp = batch[i - 1];
        for (int g = bp + 1; g <= b; ++g) gstart[g] = i;
    }
    if (i == N_NODES - 1) {
        for (int g = b + 1; g <= NUM_GRAPHS; ++g) gstart[g] = N_NODES;
    }
}

// ---------------- CSR build pass 1: LDS-binned, full-line flush ----------------

__global__ __launch_bounds__(256) void k_p1(const int* __restrict__ src,
                                            const int* __restrict__ dst,
                                            unsigned* __restrict__ slab,
                                            int* __restrict__ gcnt) {
    __shared__ unsigned bl[NBIN * CAP1];   // 62.7 KB
    __shared__ int c1[NBIN];

    const int ch = blockIdx.x;
    const int t  = threadIdx.x;
    for (int i = t; i < NBIN; i += 256) c1[i] = 0;
    __syncthreads();

    const int e0 = ch * CH_E;
    const int e1 = (e0 + CH_E < N_EDGES) ? e0 + CH_E : N_EDGES;
    for (int e = e0 + t; e < e1; e += 256) {
        int d = dst[e];
        int s = src[e];
        int b = d >> BINSHIFT;
        int pos = atomicAdd(&c1[b], 1);
        if (pos < CAP1)
            bl[b * CAP1 + pos] = ((unsigned)s << BINSHIFT) | (unsigned)(d & (BINSZ - 1));
    }
    __syncthreads();

    const int wv = t >> 6, ln = t & 63;
    for (int b = wv; b < NBIN; b += 4) {
        int n = c1[b]; n = n < CAP1 ? n : CAP1;
        unsigned* sp = &slab[((size_t)b * NCH + ch) * CAP1];
        for (int i = ln; i < n; i += 64) sp[i] = bl[b * CAP1 + i];
        if (ln == 0) gcnt[b * NCH + ch] = n;
    }
}

// ---------------- bin base scan (tiny) + zero the pool accumulator ----------------

__global__ void k_binscan(const int* __restrict__ gcnt, int* __restrict__ binbase,
                          float* __restrict__ part) {
    __shared__ int T[NBIN];
    int t = threadIdx.x;
    for (int i = t; i < NUM_GRAPHS * HIDDEN; i += 128) part[i] = 0.f;
    if (t < NBIN) {
        int s = 0;
        for (int c = 0; c < NCH; ++c) s += gcnt[t * NCH + c];
        T[t] = s;
    }
    __syncthreads();
    if (t == 0) {
        int run = 0;
        for (int b = 0; b < NBIN; ++b) { binbase[b] = run; run += T[b]; }
        binbase[NBIN] = run;
    }
}

// ---------------- CSR build pass 2: per-bin finalize, latency-parallel ----------------

__global__ __launch_bounds__(1024) void k_p2(const unsigned* __restrict__ slab,
                                             const int* __restrict__ gcnt,
                                             const int* __restrict__ binbase,
                                             int* __restrict__ csr_src,
                                             int* __restrict__ offs,
                                             float* __restrict__ dinv) {
    __shared__ unsigned eb[CAP2];          // 72 KB
    __shared__ int cnt2[BINSZ];
    __shared__ int off2[BINSZ];
    __shared__ int cur[BINSZ];
    __shared__ int choff[NCH + 1];
    __shared__ int csc[256];

    const int bin = blockIdx.x;
    const int t   = threadIdx.x;

    cnt2[t] = 0; cur[t] = 0;               // blockDim == BINSZ == 1024
    if (t < 256) csc[t] = (t < NCH) ? gcnt[bin * NCH + t] : 0;
    __syncthreads();

    for (int off = 1; off < 256; off <<= 1) {
        int add = 0;
        if (t < 256 && t >= off) add = csc[t - off];
        __syncthreads();
        if (t < 256) csc[t] += add;
        __syncthreads();
    }
    if (t < NCH) {
        int v = gcnt[bin * NCH + t];
        choff[t] = csc[t] - v;             // exclusive
        if (t == NCH - 1) choff[NCH] = csc[t];
    }
    __syncthreads();
    int total = choff[NCH]; total = total < CAP2 ? total : CAP2;

    const int wv = t >> 6, ln = t & 63;
    for (int c = wv; c < NCH; c += 16) {
        int o = choff[c];
        int n = choff[c + 1] - o;
        const unsigned* sp = &slab[((size_t)bin * NCH + c) * CAP1];
        for (int i = ln; i < n; i += 64) {
            int idx = o + i;
            if (idx < CAP2) {
                unsigned v = sp[i];
                eb[idx] = v;
                atomicAdd(&cnt2[v & (BINSZ - 1)], 1);
            }
        }
    }
    __syncthreads();

    int mycnt = cnt2[t];
    off2[t] = mycnt;
    __syncthreads();
    for (int off = 1; off < BINSZ; off <<= 1) {
        int add = (t >= off) ? off2[t - off] : 0;
        __syncthreads();
        off2[t] += add;
        __syncthreads();
    }
    int excl = off2[t] - mycnt;
    __syncthreads();
    off2[t] = excl;
    __syncthreads();

    const int base  = binbase[bin];
    const int node0 = bin << BINSHIFT;
    int node = node0 + t;
    if (node < N_NODES) {
        offs[node] = base + excl;
        dinv[node] = rsqrtf((float)(mycnt + 1));   // +1 self-loop
    }
    if (bin == NBIN - 1 && t == 0) offs[N_NODES] = base + total;
    __syncthreads();

    for (int i = t; i < total; i += 1024) {
        unsigned v = eb[i];
        int lo = v & (BINSZ - 1);
        int p = atomicAdd(&cur[lo], 1);
        csr_src[base + off2[lo] + p] = (int)(v >> BINSHIFT);
    }
}

// ---------------- W prep: Wt[l][c][k] = bf16(W[l][k][c]) (once) ----------------

__global__ __launch_bounds__(256) void k_wprep(const float* __restrict__ Ws,
                                               unsigned short* __restrict__ Wt_g) {
    int idx = blockIdx.x * 256 + threadIdx.x;
    if (idx >= 2 * HIDDEN * HIDDEN) return;
    int l = idx >> 14, rem = idx & 16383, c = rem >> 7, k = rem & 127;
    Wt_g[idx] = f2bf(Ws[l * HIDDEN * HIDDEN + k * HIDDEN + c]);
}

// ---------------- MFMA GEMM: Hb8 = fp8(8 * dinv ⊙ (X @ W)) ----------------

template <bool IN_F32>
__global__ __launch_bounds__(256) void k_gemm(const void* __restrict__ Xin,
                                              const unsigned short* __restrict__ Wt_g,
                                              const float* __restrict__ dinv,
                                              unsigned char* __restrict__ Hb8) {
    __shared__ char sm[70144];
    unsigned short* Xl = (unsigned short*)sm;            // [128][136] bf16
    unsigned short* Wl = (unsigned short*)(sm + 34816);  // [128][136] bf16
    float*          Dl = (float*)(sm + 69632);           // [128] f32
    unsigned char*  Hl = (unsigned char*)sm;             // [128][128] fp8 (aliases Xl)

    const int t    = threadIdx.x;
    const int row0 = blockIdx.x * 128;
    const float* Xf = (const float*)Xin;
    const unsigned short* Xb = (const unsigned short*)Xin;

    #pragma unroll
    for (int i = 0; i < 8; ++i) {
        int idx = t + i * 256;
        int r = idx >> 4, kq = idx & 15;
        int rg = row0 + r; rg = rg < N_NODES ? rg : N_NODES - 1;
        if (IN_F32) {
            float4 xa = *(const float4*)&Xf[(size_t)rg * HIDDEN + kq * 8];
            float4 xb = *(const float4*)&Xf[(size_t)rg * HIDDEN + kq * 8 + 4];
            unsigned short o[8];
            o[0] = f2bf(xa.x); o[1] = f2bf(xa.y); o[2] = f2bf(xa.z); o[3] = f2bf(xa.w);
            o[4] = f2bf(xb.x); o[5] = f2bf(xb.y); o[6] = f2bf(xb.z); o[7] = f2bf(xb.w);
            *(uint4*)&Xl[r * 136 + kq * 8] = *(uint4*)o;
        } else {
            *(uint4*)&Xl[r * 136 + kq * 8] = *(const uint4*)&Xb[(size_t)rg * HIDDEN + kq * 8];
        }
        *(uint4*)&Wl[r * 136 + kq * 8] = *(const uint4*)&Wt_g[r * HIDDEN + kq * 8];
    }
    if (t < 128) {
        int rg = row0 + t; rg = rg < N_NODES ? rg : N_NODES - 1;
        Dl[t] = dinv[rg] * 8.f;
    }
    __syncthreads();

    const int lane = t & 63;
    const int wv   = t >> 6;
    const int rb0  = wv * 32;
    const int arow = lane & 15;
    const int kgrp = lane >> 4;

    f32x4v c[2][8];
    #pragma unroll
    for (int rb = 0; rb < 2; ++rb)
        #pragma unroll
        for (int cb = 0; cb < 8; ++cb)
            c[rb][cb] = (f32x4v){0.f, 0.f, 0.f, 0.f};

    #pragma unroll
    for (int kc = 0; kc < 4; ++kc) {
        int kbase = kc * 32 + kgrp * 8;
        bf16x8 a0 = *(const bf16x8*)&Xl[(rb0 + arow) * 136 + kbase];
        bf16x8 a1 = *(const bf16x8*)&Xl[(rb0 + 16 + arow) * 136 + kbase];
        #pragma unroll
        for (int cb = 0; cb < 8; ++cb) {
            bf16x8 b = *(const bf16x8*)&Wl[(cb * 16 + arow) * 136 + kbase];
            c[0][cb] = __builtin_amdgcn_mfma_f32_16x16x32_bf16(a0, b, c[0][cb], 0, 0, 0);
            c[1][cb] = __builtin_amdgcn_mfma_f32_16x16x32_bf16(a1, b, c[1][cb], 0, 0, 0);
        }
    }
    __syncthreads();

    const int col   = lane & 15;
    const int rbase = (lane >> 4) * 4;
    #pragma unroll
    for (int rb = 0; rb < 2; ++rb) {
        #pragma unroll
        for (int cb = 0; cb < 8; ++cb) {
            int rl = rb0 + rb * 16 + rbase;
            f32x4v cv = c[rb][cb];
            unsigned p = enc4_e4m3(cv[0] * Dl[rl], cv[1] * Dl[rl + 1],
                                   cv[2] * Dl[rl + 2], cv[3] * Dl[rl + 3]);
            int cc = cb * 16 + col;
            Hl[(rl + 0) * 128 + cc] = (unsigned char)(p & 0xFF);
            Hl[(rl + 1) * 128 + cc] = (unsigned char)((p >> 8) & 0xFF);
            Hl[(rl + 2) * 128 + cc] = (unsigned char)((p >> 16) & 0xFF);
            Hl[(rl + 3) * 128 + cc] = (unsigned char)((p >> 24) & 0xFF);
        }
    }
    __syncthreads();

    #pragma unroll
    for (int i = 0; i < 4; ++i) {
        int q = t + i * 256;
        int r = q >> 3, qq = q & 7;
        int row = row0 + r;
        if (row < N_NODES)
            *(uint4*)&Hb8[(size_t)row * HIDDEN + qq * 16] = *(const uint4*)&Hl[r * 128 + qq * 16];
    }
}

// ---------------- fused aggregation over pre-scaled fp8 rows ----------------
// 8 lanes per node, dwordx4/lane -> one FULL row per 8-lane group per load
// instruction (8 lines per wave-instr); dual accumulators -> ~16 lines in
// flight per wave. 32 nodes per 256-thr block.
// OUT_MODE: 1 = fp8 (scaled by dinv*out_enc), 2 = bf16

template <int OUT_MODE, bool BIAS, bool RELU>
__global__ __launch_bounds__(256) void k_aggregate(const unsigned char* __restrict__ Hb8,
                                                   const int* __restrict__ offs,
                                                   const int* __restrict__ csr_src,
                                                   const float* __restrict__ dinv,
                                                   const float* __restrict__ bias,
                                                   void* __restrict__ outv,
                                                   float in_dec, float out_enc) {
    int g    = threadIdx.x >> 3;       // node-in-block 0..31
    int lane = threadIdx.x & 7;        // 8 lanes per node
    int node = blockIdx.x * 32 + g;    // 3125 * 32 == 100000 exactly
    int c16  = lane * 16;              // 16 fp8 columns per lane

    float di = dinv[node];
    float accA[16], accB[16];
    dec16(*(const uint4*)&Hb8[(size_t)node * HIDDEN + c16], accA);
    #pragma unroll
    for (int i = 0; i < 16; ++i) accB[i] = 0.f;

    int j0 = offs[node], j1 = offs[node + 1];
    int j = j0;
    #pragma unroll 2
    for (; j + 2 <= j1; j += 2) {
        int s0 = csr_src[j], s1 = csr_src[j + 1];
        uint4 v0 = *(const uint4*)&Hb8[(size_t)s0 * HIDDEN + c16];
        uint4 v1 = *(const uint4*)&Hb8[(size_t)s1 * HIDDEN + c16];
        float f0[16], f1[16];
        dec16(v0, f0); dec16(v1, f1);
        #pragma unroll
        for (int i = 0; i < 16; ++i) { accA[i] += f0[i]; accB[i] += f1[i]; }
    }
    if (j < j1) {
        uint4 v0 = *(const uint4*)&Hb8[(size_t)csr_src[j] * HIDDEN + c16];
        float f0[16];
        dec16(v0, f0);
        #pragma unroll
        for (int i = 0; i < 16; ++i) accA[i] += f0[i];
    }

    float ms = di * in_dec;
    float acc[16];
    #pragma unroll
    for (int i = 0; i < 16; ++i) acc[i] = (accA[i] + accB[i]) * ms;
    if (BIAS) {
        #pragma unroll
        for (int q = 0; q < 4; ++q) {
            float4 bv = *(const float4*)&bias[c16 + q * 4];
            acc[q * 4 + 0] += bv.x; acc[q * 4 + 1] += bv.y;
            acc[q * 4 + 2] += bv.z; acc[q * 4 + 3] += bv.w;
        }
    }
    if (RELU) {
        #pragma unroll
        for (int i = 0; i < 16; ++i) acc[i] = fmaxf(acc[i], 0.f);
    }
    if (OUT_MODE == 1) {
        float es = di * out_enc;
        uint4 p;
        p.x = enc4_e4m3(acc[0] * es,  acc[1] * es,  acc[2] * es,  acc[3] * es);
        p.y = enc4_e4m3(acc[4] * es,  acc[5] * es,  acc[6] * es,  acc[7] * es);
        p.z = enc4_e4m3(acc[8] * es,  acc[9] * es,  acc[10] * es, acc[11] * es);
        p.w = enc4_e4m3(acc[12] * es, acc[13] * es, acc[14] * es, acc[15] * es);
        *(uint4*)&((unsigned char*)outv)[(size_t)node * HIDDEN + c16] = p;
    } else {
        unsigned short o[16];
        #pragma unroll
        for (int i = 0; i < 16; ++i) o[i] = f2bf(acc[i]);
        *(uint4*)&((unsigned short*)outv)[(size_t)node * HIDDEN + c16]     = *(uint4*)&o[0];
        *(uint4*)&((unsigned short*)outv)[(size_t)node * HIDDEN + c16 + 8] = *(uint4*)&o[8];
    }
}

// ---------------- fused layer-2 aggregate + mean-pool accumulate ----------------
// x3[node] = dinv*Σ/32 never materializes: 32-node block reduces rows in LDS
// (segmented by graph id; batch is sorted) then <=128+eps atomicAdds per block.

__global__ __launch_bounds__(256) void k_aggpool(const unsigned char* __restrict__ Hb8,
                                                 const int* __restrict__ offs,
                                                 const int* __restrict__ csr_src,
                                                 const float* __restrict__ dinv,
                                                 const int* __restrict__ batch,
                                                 float* __restrict__ part,
                                                 float in_dec) {
    __shared__ float lacc[32][128];   // 16 KB
    __shared__ int gid[32];

    int g    = threadIdx.x >> 3;       // node-in-block 0..31
    int lane = threadIdx.x & 7;
    int node = blockIdx.x * 32 + g;
    int c16  = lane * 16;

    float di = dinv[node];
    float accA[16], accB[16];
    dec16(*(const uint4*)&Hb8[(size_t)node * HIDDEN + c16], accA);
    #pragma unroll
    for (int i = 0; i < 16; ++i) accB[i] = 0.f;

    int j0 = offs[node], j1 = offs[node + 1];
    int j = j0;
    #pragma unroll 2
    for (; j + 2 <= j1; j += 2) {
        int s0 = csr_src[j], s1 = csr_src[j + 1];
        uint4 v0 = *(const uint4*)&Hb8[(size_t)s0 * HIDDEN + c16];
        uint4 v1 = *(const uint4*)&Hb8[(size_t)s1 * HIDDEN + c16];
        float f0[16], f1[16];
        dec16(v0, f0); dec16(v1, f1);
        #pragma unroll
        for (int i = 0; i < 16; ++i) { accA[i] += f0[i]; accB[i] += f1[i]; }
    }
    if (j < j1) {
        uint4 v0 = *(const uint4*)&Hb8[(size_t)csr_src[j] * HIDDEN + c16];
        float f0[16];
        dec16(v0, f0);
        #pragma unroll
        for (int i = 0; i < 16; ++i) accA[i] += f0[i];
    }

    float ms = di * in_dec;
    #pragma unroll
    for (int i = 0; i < 16; ++i) lacc[g][c16 + i] = (accA[i] + accB[i]) * ms;
    if (lane == 0) gid[g] = batch[node];
    __syncthreads();

    if (threadIdx.x < 128) {
        int c = threadIdx.x;
        float run = 0.f;
        int curg = gid[0];
        #pragma unroll 4
        for (int r = 0; r < 32; ++r) {
            int gg = gid[r];
            if (gg != curg) {
                atomicAdd(&part[curg * HIDDEN + c], run);
                run = 0.f; curg = gg;
            }
            run += lacc[r][c];
        }
        atomicAdd(&part[curg * HIDDEN + c], run);
    }
}

// ---------------- final: out = ((part/cnt) @ W2 + b2) @ linW + linb ----------------

__global__ void k_final(const float* __restrict__ part, const int* __restrict__ gstart,
                        const float* __restrict__ W2, const float* __restrict__ b2,
                        const float* __restrict__ linW, const float* __restrict__ linb,
                        float* __restrict__ out) {
    __shared__ float m[HIDDEN];
    __shared__ float t[HIDDEN];
    int g = blockIdx.x;
    int c = threadIdx.x;
    float cnt = fmaxf((float)(gstart[g + 1] - gstart[g]), 1.0f);
    m[c] = part[g * HIDDEN + c] / cnt;
    __syncthreads();
    float acc = b2[c];
    #pragma unroll 4
    for (int k = 0; k < HIDDEN; ++k) acc += m[k] * W2[k * HIDDEN + c];
    t[c] = acc;
    __syncthreads();
    if (c < 16) {
        float o = linb[c];
        #pragma unroll 4
        for (int k = 0; k < HIDDEN; ++k) o += t[k] * linW[k * 16 + c];
        out[g * 16 + c] = o;
    }
}

// ---------------- launch ----------------

extern "C" void kernel_launch(void* const* d_in, const int* in_sizes, int n_in,
                              void* d_out, int out_size, void* d_ws, size_t ws_size,
                              hipStream_t stream) {
    const float* x     = (const float*)d_in[0];
    const int*   edge  = (const int*)d_in[1];   // [2, E] flat
    const int*   batch = (const int*)d_in[2];
    const float* Ws    = (const float*)d_in[3]; // [3,128,128]
    const float* bs    = (const float*)d_in[4]; // [3,128]
    const float* linW  = (const float*)d_in[5]; // [128,16]
    const float* linb  = (const float*)d_in[6]; // [16]
    float* out = (float*)d_out;

    const int* src = edge;
    const int* dst = edge + N_EDGES;

    // workspace layout (unchanged offsets)
    float* bufA = (float*)d_ws;
    unsigned* slab = (unsigned*)bufA;                 // CSR-build scratch, dead after p2
    float* bufBreg = bufA + (size_t)N_NODES * HIDDEN;
    unsigned char* hb8  = (unsigned char*)bufBreg;                                    // fp8
    unsigned char* x2b8 = (unsigned char*)bufBreg + (size_t)N_NODES * HIDDEN;         // fp8
    unsigned short* x1b = (unsigned short*)((unsigned char*)bufBreg + (size_t)2 * N_NODES * HIDDEN); // bf16
    float* dinv = bufBreg + (size_t)N_NODES * HIDDEN;
    float* part = dinv + N_NODES;                     // uses 64*128 of the reserved region
    int* offs    = (int*)(part + NUM_GRAPHS * POOL_CHUNKS * HIDDEN); // N+1
    int* csr_src = offs + N_NODES + 1;                // E
    int* gstart  = csr_src + N_EDGES;                 // NUM_GRAPHS+1
    int* gcnt    = gstart + NUM_GRAPHS + 1;           // NBIN*NCH
    int* binbase = gcnt + NBIN * NCH;                 // NBIN+1
    unsigned short* Wt_g = (unsigned short*)(binbase + NBIN + 1); // 2*128*128 bf16

    const int NB_N    = (N_NODES + 255) / 256;   // 391
    const int NB_AGG  = N_NODES / 32;            // 3125 (32 nodes per 256-thr block)
    const int NB_GEMM = (N_NODES + 127) / 128;   // 782

    // CSR build (also produces offs, dinv, zeroed part) — LDS-staged, no global atomics
    k_p1<<<NCH, 256, 0, stream>>>(src, dst, slab, gcnt);
    k_binscan<<<1, 128, 0, stream>>>(gcnt, binbase, part);
    k_p2<<<NBIN, 1024, 0, stream>>>(slab, gcnt, binbase, csr_src, offs, dinv);
    k_gbounds<<<NB_N, 256, 0, stream>>>(batch, gstart);
    k_wprep<<<(2 * HIDDEN * HIDDEN + 255) / 256, 256, 0, stream>>>(Ws, Wt_g);

    // layer 0: hb8 = fp8(8*dinv*(x@W0)) ; x1b = bf16(relu(dinv*Σ/8 + b0))
    k_gemm<true><<<NB_GEMM, 256, 0, stream>>>(x, Wt_g, dinv, hb8);
    k_aggregate<2, true, true><<<NB_AGG, 256, 0, stream>>>(hb8, offs, csr_src, dinv, bs, x1b, 0.125f, 0.f);

    // layer 1: hb8 = fp8(8*dinv*(x1@W1)) ; x2' = fp8(32*dinv*relu(dinv*Σ/8 + b1))
    k_gemm<false><<<NB_GEMM, 256, 0, stream>>>(x1b, Wt_g + HIDDEN * HIDDEN, dinv, hb8);
    k_aggregate<1, true, true><<<NB_AGG, 256, 0, stream>>>(hb8, offs, csr_src, dinv, bs + HIDDEN, x2b8, 0.125f, 32.f);

    // layer 2 (fused): part[g] += Σ_{node in g} dinv*Σ/32  (x3 never materializes)
    k_aggpool<<<NB_AGG, 256, 0, stream>>>(x2b8, offs, csr_src, dinv, batch, part, 0.03125f);

    k_final<<<NUM_GRAPHS, HIDDEN, 0, stream>>>(part, gstart,
                                               Ws + 2 * HIDDEN * HIDDEN, bs + 2 * HIDDEN,
                                               linW, linb, out);
}